// Round 17
// baseline (51.645 us; speedup 1.0000x reference)
//
#include <hip/hip_runtime.h>
#include <hip/hip_fp16.h>

#define G_DIM 16384
#define N_BATCH 2048
#define IN_DIM 1024
#define NLAYER 6
#define THREADS 1024
#define NPAIR 8                // gate-pairs per thread (16 gates)
#define NCHUNK 4               // chunks of 2 pairs
#define ROWS 4                 // batch rows per block

struct Ptrs {
    const int*   idx[NLAYER];
    const float* w[NLAYER];
};

__device__ __forceinline__ unsigned f2h(float a, float b) {
    __half2 h = __floats2half2_rn(a, b);
    return *reinterpret_cast<unsigned*>(&h);
}

// ---- v_fma_mix helpers: f16/f32 operands, fma in f32 ----
__device__ __forceinline__ float mix_hlh(unsigned a, unsigned b, unsigned c) {
    float d;
    asm("v_fma_mix_f32 %0, %1, %2, %3 op_sel:[1,0,1] op_sel_hi:[1,1,1]"
        : "=v"(d) : "v"(a), "v"(b), "v"(c));
    return d;
}
__device__ __forceinline__ float mix_hhh(unsigned a, unsigned b, unsigned c) {
    float d;
    asm("v_fma_mix_f32 %0, %1, %2, %3 op_sel:[1,1,1] op_sel_hi:[1,1,1]"
        : "=v"(d) : "v"(a), "v"(b), "v"(c));
    return d;
}
__device__ __forceinline__ float mix_lll(unsigned a, unsigned b, unsigned c) {
    float d;
    asm("v_fma_mix_f32 %0, %1, %2, %3 op_sel:[0,0,0] op_sel_hi:[1,1,1]"
        : "=v"(d) : "v"(a), "v"(b), "v"(c));
    return d;
}
__device__ __forceinline__ float mix_lhl(unsigned a, unsigned b, unsigned c) {
    float d;
    asm("v_fma_mix_f32 %0, %1, %2, %3 op_sel:[0,1,0] op_sel_hi:[1,1,1]"
        : "=v"(d) : "v"(a), "v"(b), "v"(c));
    return d;
}
__device__ __forceinline__ float mix_alo(float u, unsigned A, float v) {
    float d;
    asm("v_fma_mix_f32 %0, %1, %2, %3 op_sel:[0,0,0] op_sel_hi:[0,1,0]"
        : "=v"(d) : "v"(u), "v"(A), "v"(v));
    return d;
}
__device__ __forceinline__ float mix_ahi(float u, unsigned A, float v) {
    float d;
    asm("v_fma_mix_f32 %0, %1, %2, %3 op_sel:[0,1,0] op_sel_hi:[0,1,0]"
        : "=v"(d) : "v"(u), "v"(A), "v"(v));
    return d;
}
__device__ __forceinline__ unsigned mix_pack(float u0, float v0, float u1, float v1,
                                             unsigned A) {
    unsigned t;
    asm("v_fma_mixlo_f16 %0, %1, %2, %3 op_sel:[0,0,0] op_sel_hi:[0,1,0]"
        : "=v"(t) : "v"(u0), "v"(A), "v"(v0));
    asm("v_fma_mixhi_f16 %0, %1, %2, %3 op_sel:[0,1,0] op_sel_hi:[0,1,0]"
        : "+v"(t) : "v"(u1), "v"(A), "v"(v1));
    return t;
}

struct PairG { uint2 A0, B0, A1, B1; };   // gathered activations for a gate pair

#define GATHER(G, PK)                                     \
    do {                                                  \
        (G).A0 = buf[(PK).x & 0xFFFFu];                   \
        (G).B0 = buf[(PK).x >> 16];                       \
        (G).A1 = buf[(PK).y & 0xFFFFu];                   \
        (G).B1 = buf[(PK).y >> 16];                       \
    } while (0)

__device__ __forceinline__ uint2 gate_fma(uint2 Au, uint2 Bu, unsigned c01, unsigned c23) {
    const float u0 = mix_hlh(c23, Bu.x, c01);
    const float u1 = mix_hhh(c23, Bu.x, c01);
    const float v0 = mix_lll(c23, Bu.x, c01);
    const float v1 = mix_lhl(c23, Bu.x, c01);
    const float u2 = mix_hlh(c23, Bu.y, c01);
    const float u3 = mix_hhh(c23, Bu.y, c01);
    const float v2 = mix_lll(c23, Bu.y, c01);
    const float v3 = mix_lhl(c23, Bu.y, c01);
    const unsigned t01 = mix_pack(u0, v0, u1, v1, Au.x);
    const unsigned t23 = mix_pack(u2, v2, u3, v3, Au.y);
    return make_uint2(t01, t23);
}
__device__ __forceinline__ void gate_acc(uint2 Au, uint2 Bu, unsigned c01, unsigned c23,
                                         float lw, float& a0, float& a1, float& a2, float& a3) {
    const float u0 = mix_hlh(c23, Bu.x, c01);
    const float u1 = mix_hhh(c23, Bu.x, c01);
    const float v0 = mix_lll(c23, Bu.x, c01);
    const float v1 = mix_lhl(c23, Bu.x, c01);
    const float u2 = mix_hlh(c23, Bu.y, c01);
    const float u3 = mix_hhh(c23, Bu.y, c01);
    const float v2 = mix_lll(c23, Bu.y, c01);
    const float v3 = mix_lhl(c23, Bu.y, c01);
    a0 = fmaf(mix_alo(u0, Au.x, v0), lw, a0);
    a1 = fmaf(mix_ahi(u1, Au.x, v1), lw, a1);
    a2 = fmaf(mix_alo(u2, Au.y, v2), lw, a2);
    a3 = fmaf(mix_ahi(u3, Au.y, v3), lw, a3);
}

__device__ __forceinline__ float4 softmax_coef(const float* __restrict__ w, int g) {
    float v[16];
    float m = -1e30f;
#pragma unroll
    for (int k = 0; k < 16; ++k) { v[k] = w[k * G_DIM + g]; m = fmaxf(m, v[k]); }
    float s = 0.f;
#pragma unroll
    for (int k = 0; k < 16; ++k) { v[k] = expf(v[k] - m); s += v[k]; }
    const float inv = 1.f / s;
    float4 c;
    c.x = (v[8]+v[9]+v[10]+v[11]+v[12]+v[13]+v[14]+v[15]) * inv;
    c.y = (v[2]+v[3]+v[6]+v[7] - v[8]-v[9]-v[12]-v[13]) * inv;
    c.z = (v[4]+v[5]+v[6]+v[7] - v[8]-v[9]-v[10]-v[11]) * inv;
    c.w = (v[1]-v[2]-v[4]-2.f*v[6]-v[7]+v[8]+2.f*v[9]+v[11]+v[13]-v[14]) * inv;
    return c;
}

// ---- precompute: coef[l][g] as half4 (uint2) and packed idx (lo16=A, hi16=B) ----
__global__ __launch_bounds__(256) void pack_kernel(Ptrs P, uint2* __restrict__ hcf,
                                                   unsigned* __restrict__ sidx) {
    const int g = blockIdx.x * blockDim.x + threadIdx.x;
    const int l = blockIdx.y;
    const float4 c = softmax_coef(P.w[l], g);
    hcf[(size_t)l * G_DIM + g] = make_uint2(f2h(c.x, c.y), f2h(c.z, c.w));
    const int2 p = ((const int2*)P.idx[l])[g];
    sidx[(size_t)l * G_DIM + g] = (unsigned)p.x | ((unsigned)p.y << 16);
}

// ---- main fused kernel (R15 skeleton, gather pipeline deepened to 2 pairs):
//      gather pair i+2 issues while pair i computes (3-stage PairG rotation);
//      idx+coef streams prefetched two chunks ahead. ----
__global__ __launch_bounds__(THREADS) void fused_ws_kernel(
    const float* __restrict__ x,
    const uint2* __restrict__ hcf,
    const unsigned* __restrict__ sidx,
    const float* __restrict__ lin_w,
    const float* __restrict__ lin_b,
    float* __restrict__ out)
{
    __shared__ uint4 buf4[G_DIM / 2];        // 128 KB
    __shared__ float red[ROWS][THREADS / 64];
    uint2* buf = (uint2*)buf4;               // per-gate view {h2(r0,r1), h2(r2,r3)}

    const int tid  = threadIdx.x;
    const int row0 = blockIdx.x * ROWS;

    for (int i = tid; i < IN_DIM; i += THREADS) {
        const float r0 = x[(size_t)(row0 + 0) * IN_DIM + i];
        const float r1 = x[(size_t)(row0 + 1) * IN_DIM + i];
        const float r2 = x[(size_t)(row0 + 2) * IN_DIM + i];
        const float r3 = x[(size_t)(row0 + 3) * IN_DIM + i];
        buf[i] = make_uint2(f2h(r0, r1), f2h(r2, r3));
    }

    const uint2*  __restrict__ sidx2 = (const uint2*)sidx;   // idx per pair
    const uint4*  __restrict__ hcf4  = (const uint4*)hcf;    // coef per pair
    const float2* __restrict__ lw2   = (const float2*)lin_w; // lin_w per pair

    // prologue: layer-0 chunk0+chunk1 idx AND coef in flight while rows stage
    uint2 pkA[2], pkB[2];
    uint4 ccA[2], ccB[2];
#pragma unroll
    for (int j = 0; j < 2; ++j) {
        pkA[j] = sidx2[tid + j * THREADS];
        pkB[j] = sidx2[tid + (2 + j) * THREADS];
        ccA[j] = hcf4 [tid + j * THREADS];
        ccB[j] = hcf4 [tid + (2 + j) * THREADS];
    }

    __syncthreads();

    float a0 = 0.f, a1 = 0.f, a2 = 0.f, a3 = 0.f;

#pragma unroll
    for (int l = 0; l < NLAYER; ++l) {
        uint4 o[NPAIR];
        PairG G0, G1, G2;                    // 3-stage gather pipeline
        GATHER(G0, pkA[0]);                  // pair 0
        GATHER(G1, pkA[1]);                  // pair 1

#pragma unroll
        for (int ch = 0; ch < NCHUNK; ++ch) {
            // issue idx+coef two chunks ahead (wrapping into the next layer)
            uint2 pkC[2];
            uint4 ccC[2];
            const bool haveC = (ch + 2 < NCHUNK) || (l + 1 < NLAYER);
            if (haveC) {
                const int lc  = (ch + 2 < NCHUNK) ? l : l + 1;
                const int cc_ = (ch + 2 < NCHUNK) ? ch + 2 : ch + 2 - NCHUNK;
                const uint2* sC = sidx2 + (size_t)lc * (G_DIM / 2);
                const uint4* cC = hcf4  + (size_t)lc * (G_DIM / 2);
#pragma unroll
                for (int j = 0; j < 2; ++j) {
                    pkC[j] = sC[tid + (cc_ * 2 + j) * THREADS];
                    ccC[j] = cC[tid + (cc_ * 2 + j) * THREADS];
                }
            }
            float2 lwp[2];
            if (l == NLAYER - 1) {
#pragma unroll
                for (int j = 0; j < 2; ++j) lwp[j] = lw2[tid + (ch * 2 + j) * THREADS];
            }

            // pair A (= ch*2): gather pair +2 (pkB[0]), compute G0
            if (ch + 1 < NCHUNK) GATHER(G2, pkB[0]);
            if (l < NLAYER - 1) {
                const uint2 g0 = gate_fma(G0.A0, G0.B0, ccA[0].x, ccA[0].y);
                const uint2 g1 = gate_fma(G0.A1, G0.B1, ccA[0].z, ccA[0].w);
                o[ch * 2] = make_uint4(g0.x, g0.y, g1.x, g1.y);
            } else {
                gate_acc(G0.A0, G0.B0, ccA[0].x, ccA[0].y, lwp[0].x, a0, a1, a2, a3);
                gate_acc(G0.A1, G0.B1, ccA[0].z, ccA[0].w, lwp[0].y, a0, a1, a2, a3);
            }
            G0 = G2;
            // pair B (= ch*2+1): gather pair +2 (pkB[1]), compute G1
            if (ch + 1 < NCHUNK) GATHER(G2, pkB[1]);
            if (l < NLAYER - 1) {
                const uint2 g0 = gate_fma(G1.A0, G1.B0, ccA[1].x, ccA[1].y);
                const uint2 g1 = gate_fma(G1.A1, G1.B1, ccA[1].z, ccA[1].w);
                o[ch * 2 + 1] = make_uint4(g0.x, g0.y, g1.x, g1.y);
            } else {
                gate_acc(G1.A0, G1.B0, ccA[1].x, ccA[1].y, lwp[1].x, a0, a1, a2, a3);
                gate_acc(G1.A1, G1.B1, ccA[1].z, ccA[1].w, lwp[1].y, a0, a1, a2, a3);
            }
            G1 = G2;

            // rotate stream registers
#pragma unroll
            for (int j = 0; j < 2; ++j) {
                pkA[j] = pkB[j];
                ccA[j] = ccB[j];
                if (haveC) { pkB[j] = pkC[j]; ccB[j] = ccC[j]; }
            }
        }

        if (l < NLAYER - 1) {
            __syncthreads();   // all reads of this layer done
#pragma unroll
            for (int p = 0; p < NPAIR; ++p) buf4[tid + p * THREADS] = o[p];
            __syncthreads();   // layer fully materialized
        }
    }

    // cross-lane / cross-wave reduction (4 rows)
#pragma unroll
    for (int off = 32; off > 0; off >>= 1) {
        a0 += __shfl_down(a0, off);
        a1 += __shfl_down(a1, off);
        a2 += __shfl_down(a2, off);
        a3 += __shfl_down(a3, off);
    }
    const int lane = tid & 63, wid = tid >> 6;
    if (lane == 0) { red[0][wid] = a0; red[1][wid] = a1; red[2][wid] = a2; red[3][wid] = a3; }
    __syncthreads();
    if (tid < ROWS) {
        float s = 0.f;
#pragma unroll
        for (int k = 0; k < THREADS / 64; ++k) s += red[tid][k];
        out[row0 + tid] = s + lin_b[0];
    }
}

// ---- fallback (small ws): exact f32, inline softmax (correctness only) ----
__global__ __launch_bounds__(THREADS, 1) void fused_fallback_kernel(
    const float* __restrict__ x, Ptrs P,
    const float* __restrict__ lin_w, const float* __restrict__ lin_b,
    float* __restrict__ out)
{
    __shared__ float2 buf[G_DIM];
    __shared__ float red0[THREADS / 64];
    __shared__ float red1[THREADS / 64];
    const int tid  = threadIdx.x;
    const int row0 = blockIdx.x * 2;
    for (int i = tid; i < IN_DIM; i += THREADS)
        buf[i] = make_float2(x[(size_t)row0 * IN_DIM + i],
                             x[(size_t)(row0 + 1) * IN_DIM + i]);
    __syncthreads();
    float2 o[16];
    for (int l = 0; l < NLAYER; ++l) {
        const int2* __restrict__ idxl = (const int2*)P.idx[l];
#pragma unroll
        for (int i = 0; i < 16; ++i) {
            const int g = tid + i * THREADS;
            const int2 p = idxl[g];
            const float4 c = softmax_coef(P.w[l], g);
            const float2 Ap = buf[p.x];
            const float2 Bp = buf[p.y];
            o[i].x = fmaf(fmaf(c.w, Bp.x, c.y), Ap.x, fmaf(c.z, Bp.x, c.x));
            o[i].y = fmaf(fmaf(c.w, Bp.y, c.y), Ap.y, fmaf(c.z, Bp.y, c.x));
        }
        __syncthreads();
#pragma unroll
        for (int i = 0; i < 16; ++i) buf[tid + i * THREADS] = o[i];
        __syncthreads();
    }
    float a0 = 0.f, a1 = 0.f;
#pragma unroll
    for (int i = 0; i < 16; ++i) {
        const int g = tid + i * THREADS;
        const float lw = lin_w[g];
        const float2 bv = buf[g];
        a0 = fmaf(bv.x, lw, a0);
        a1 = fmaf(bv.y, lw, a1);
    }
#pragma unroll
    for (int off = 32; off > 0; off >>= 1) {
        a0 += __shfl_down(a0, off);
        a1 += __shfl_down(a1, off);
    }
    const int lane = tid & 63, wid = tid >> 6;
    if (lane == 0) { red0[wid] = a0; red1[wid] = a1; }
    __syncthreads();
    if (tid == 0) {
        float s0 = 0.f, s1 = 0.f;
#pragma unroll
        for (int k = 0; k < THREADS / 64; ++k) { s0 += red0[k]; s1 += red1[k]; }
        const float lb = lin_b[0];
        out[row0]     = s0 + lb;
        out[row0 + 1] = s1 + lb;
    }
}

extern "C" void kernel_launch(void* const* d_in, const int* in_sizes, int n_in,
                              void* d_out, int out_size, void* d_ws, size_t ws_size,
                              hipStream_t stream) {
    // layout: [x, idx0, w0, idx1, w1, ..., idx5, w5, lin_w, lin_b]
    const float* x = (const float*)d_in[0];
    Ptrs P;
    for (int l = 0; l < NLAYER; ++l) {
        P.idx[l] = (const int*)d_in[1 + 2 * l];
        P.w[l]   = (const float*)d_in[2 + 2 * l];
    }
    const float* lin_w = (const float*)d_in[13];
    const float* lin_b = (const float*)d_in[14];
    float* out = (float*)d_out;

    const size_t hcf_bytes  = (size_t)NLAYER * G_DIM * sizeof(uint2);
    const size_t sidx_bytes = (size_t)NLAYER * G_DIM * sizeof(unsigned);
    if (ws_size >= hcf_bytes + sidx_bytes) {
        uint2*    hcf  = (uint2*)d_ws;
        unsigned* sidx = (unsigned*)((char*)d_ws + hcf_bytes);
        dim3 cgrid(G_DIM / 256, NLAYER);
        pack_kernel<<<cgrid, 256, 0, stream>>>(P, hcf, sidx);
        fused_ws_kernel<<<N_BATCH / ROWS, THREADS, 0, stream>>>(
            x, hcf, sidx, lin_w, lin_b, out);
    } else {
        fused_fallback_kernel<<<N_BATCH / 2, THREADS, 0, stream>>>(
            x, P, lin_w, lin_b, out);
    }
}

// Round 18
// 50.158 us; speedup vs baseline: 1.0297x; 1.0297x over previous
//
#include <hip/hip_runtime.h>
#include <hip/hip_fp16.h>

#define G_DIM 16384
#define N_BATCH 2048
#define IN_DIM 1024
#define NLAYER 6
#define THREADS 1024
#define NPAIR 8                // gate-pairs per thread (16 gates)
#define NCHUNK 4               // chunks of 2 pairs
#define ROWS 4                 // batch rows per block

struct Ptrs {
    const int*   idx[NLAYER];
    const float* w[NLAYER];
};

__device__ __forceinline__ unsigned f2h(float a, float b) {
    __half2 h = __floats2half2_rn(a, b);
    return *reinterpret_cast<unsigned*>(&h);
}

// ---- v_fma_mix helpers: f16/f32 operands, fma in f32 ----
__device__ __forceinline__ float mix_hlh(unsigned a, unsigned b, unsigned c) {
    float d;
    asm("v_fma_mix_f32 %0, %1, %2, %3 op_sel:[1,0,1] op_sel_hi:[1,1,1]"
        : "=v"(d) : "v"(a), "v"(b), "v"(c));
    return d;
}
__device__ __forceinline__ float mix_hhh(unsigned a, unsigned b, unsigned c) {
    float d;
    asm("v_fma_mix_f32 %0, %1, %2, %3 op_sel:[1,1,1] op_sel_hi:[1,1,1]"
        : "=v"(d) : "v"(a), "v"(b), "v"(c));
    return d;
}
__device__ __forceinline__ float mix_lll(unsigned a, unsigned b, unsigned c) {
    float d;
    asm("v_fma_mix_f32 %0, %1, %2, %3 op_sel:[0,0,0] op_sel_hi:[1,1,1]"
        : "=v"(d) : "v"(a), "v"(b), "v"(c));
    return d;
}
__device__ __forceinline__ float mix_lhl(unsigned a, unsigned b, unsigned c) {
    float d;
    asm("v_fma_mix_f32 %0, %1, %2, %3 op_sel:[0,1,0] op_sel_hi:[1,1,1]"
        : "=v"(d) : "v"(a), "v"(b), "v"(c));
    return d;
}
__device__ __forceinline__ float mix_alo(float u, unsigned A, float v) {
    float d;
    asm("v_fma_mix_f32 %0, %1, %2, %3 op_sel:[0,0,0] op_sel_hi:[0,1,0]"
        : "=v"(d) : "v"(u), "v"(A), "v"(v));
    return d;
}
__device__ __forceinline__ float mix_ahi(float u, unsigned A, float v) {
    float d;
    asm("v_fma_mix_f32 %0, %1, %2, %3 op_sel:[0,1,0] op_sel_hi:[0,1,0]"
        : "=v"(d) : "v"(u), "v"(A), "v"(v));
    return d;
}
__device__ __forceinline__ unsigned mix_pack(float u0, float v0, float u1, float v1,
                                             unsigned A) {
    unsigned t;
    asm("v_fma_mixlo_f16 %0, %1, %2, %3 op_sel:[0,0,0] op_sel_hi:[0,1,0]"
        : "=v"(t) : "v"(u0), "v"(A), "v"(v0));
    asm("v_fma_mixhi_f16 %0, %1, %2, %3 op_sel:[0,1,0] op_sel_hi:[0,1,0]"
        : "+v"(t) : "v"(u1), "v"(A), "v"(v1));
    return t;
}

struct PairG { uint2 A0, B0, A1, B1; };   // gathered activations for a gate pair

#define GATHER(G, PK)                                     \
    do {                                                  \
        (G).A0 = buf[(PK).x & 0xFFFFu];                   \
        (G).B0 = buf[(PK).x >> 16];                       \
        (G).A1 = buf[(PK).y & 0xFFFFu];                   \
        (G).B1 = buf[(PK).y >> 16];                       \
    } while (0)

__device__ __forceinline__ uint2 gate_fma(uint2 Au, uint2 Bu, unsigned c01, unsigned c23) {
    const float u0 = mix_hlh(c23, Bu.x, c01);
    const float u1 = mix_hhh(c23, Bu.x, c01);
    const float v0 = mix_lll(c23, Bu.x, c01);
    const float v1 = mix_lhl(c23, Bu.x, c01);
    const float u2 = mix_hlh(c23, Bu.y, c01);
    const float u3 = mix_hhh(c23, Bu.y, c01);
    const float v2 = mix_lll(c23, Bu.y, c01);
    const float v3 = mix_lhl(c23, Bu.y, c01);
    const unsigned t01 = mix_pack(u0, v0, u1, v1, Au.x);
    const unsigned t23 = mix_pack(u2, v2, u3, v3, Au.y);
    return make_uint2(t01, t23);
}
__device__ __forceinline__ void gate_acc(uint2 Au, uint2 Bu, unsigned c01, unsigned c23,
                                         float lw, float& a0, float& a1, float& a2, float& a3) {
    const float u0 = mix_hlh(c23, Bu.x, c01);
    const float u1 = mix_hhh(c23, Bu.x, c01);
    const float v0 = mix_lll(c23, Bu.x, c01);
    const float v1 = mix_lhl(c23, Bu.x, c01);
    const float u2 = mix_hlh(c23, Bu.y, c01);
    const float u3 = mix_hhh(c23, Bu.y, c01);
    const float v2 = mix_lll(c23, Bu.y, c01);
    const float v3 = mix_lhl(c23, Bu.y, c01);
    a0 = fmaf(mix_alo(u0, Au.x, v0), lw, a0);
    a1 = fmaf(mix_ahi(u1, Au.x, v1), lw, a1);
    a2 = fmaf(mix_alo(u2, Au.y, v2), lw, a2);
    a3 = fmaf(mix_ahi(u3, Au.y, v3), lw, a3);
}

__device__ __forceinline__ float4 softmax_coef(const float* __restrict__ w, int g) {
    float v[16];
    float m = -1e30f;
#pragma unroll
    for (int k = 0; k < 16; ++k) { v[k] = w[k * G_DIM + g]; m = fmaxf(m, v[k]); }
    float s = 0.f;
#pragma unroll
    for (int k = 0; k < 16; ++k) { v[k] = expf(v[k] - m); s += v[k]; }
    const float inv = 1.f / s;
    float4 c;
    c.x = (v[8]+v[9]+v[10]+v[11]+v[12]+v[13]+v[14]+v[15]) * inv;
    c.y = (v[2]+v[3]+v[6]+v[7] - v[8]-v[9]-v[12]-v[13]) * inv;
    c.z = (v[4]+v[5]+v[6]+v[7] - v[8]-v[9]-v[10]-v[11]) * inv;
    c.w = (v[1]-v[2]-v[4]-2.f*v[6]-v[7]+v[8]+2.f*v[9]+v[11]+v[13]-v[14]) * inv;
    return c;
}

// ---- precompute: coef[l][g] as half4 (uint2) and packed idx (lo16=A, hi16=B) ----
__global__ __launch_bounds__(256) void pack_kernel(Ptrs P, uint2* __restrict__ hcf,
                                                   unsigned* __restrict__ sidx) {
    const int g = blockIdx.x * blockDim.x + threadIdx.x;
    const int l = blockIdx.y;
    const float4 c = softmax_coef(P.w[l], g);
    hcf[(size_t)l * G_DIM + g] = make_uint2(f2h(c.x, c.y), f2h(c.z, c.w));
    const int2 p = ((const int2*)P.idx[l])[g];
    sidx[(size_t)l * G_DIM + g] = (unsigned)p.x | ((unsigned)p.y << 16);
}

// ---- main fused kernel (R15, best known): 4 rows/block as f16x4 in LDS; gate
//      pairs per thread; gathers pipelined one pair ahead; idx AND coef
//      streams both prefetched TWO chunks ahead. ----
__global__ __launch_bounds__(THREADS) void fused_ws_kernel(
    const float* __restrict__ x,
    const uint2* __restrict__ hcf,
    const unsigned* __restrict__ sidx,
    const float* __restrict__ lin_w,
    const float* __restrict__ lin_b,
    float* __restrict__ out)
{
    __shared__ uint4 buf4[G_DIM / 2];        // 128 KB
    __shared__ float red[ROWS][THREADS / 64];
    uint2* buf = (uint2*)buf4;               // per-gate view {h2(r0,r1), h2(r2,r3)}

    const int tid  = threadIdx.x;
    const int row0 = blockIdx.x * ROWS;

    for (int i = tid; i < IN_DIM; i += THREADS) {
        const float r0 = x[(size_t)(row0 + 0) * IN_DIM + i];
        const float r1 = x[(size_t)(row0 + 1) * IN_DIM + i];
        const float r2 = x[(size_t)(row0 + 2) * IN_DIM + i];
        const float r3 = x[(size_t)(row0 + 3) * IN_DIM + i];
        buf[i] = make_uint2(f2h(r0, r1), f2h(r2, r3));
    }

    const uint2*  __restrict__ sidx2 = (const uint2*)sidx;   // idx per pair
    const uint4*  __restrict__ hcf4  = (const uint4*)hcf;    // coef per pair
    const float2* __restrict__ lw2   = (const float2*)lin_w; // lin_w per pair

    // prologue: layer-0 chunk0+chunk1 idx AND coef in flight while rows stage
    uint2 pkA[2], pkB[2];
    uint4 ccA[2], ccB[2];
#pragma unroll
    for (int j = 0; j < 2; ++j) {
        pkA[j] = sidx2[tid + j * THREADS];
        pkB[j] = sidx2[tid + (2 + j) * THREADS];
        ccA[j] = hcf4 [tid + j * THREADS];
        ccB[j] = hcf4 [tid + (2 + j) * THREADS];
    }

    __syncthreads();

    float a0 = 0.f, a1 = 0.f, a2 = 0.f, a3 = 0.f;

#pragma unroll
    for (int l = 0; l < NLAYER; ++l) {
        uint4 o[NPAIR];
        PairG Gc, Gn;
        GATHER(Gc, pkA[0]);                  // pair 0 of this layer

#pragma unroll
        for (int ch = 0; ch < NCHUNK; ++ch) {
            // issue idx+coef two chunks ahead (wrapping into the next layer)
            uint2 pkC[2];
            uint4 ccC[2];
            const bool haveC = (ch + 2 < NCHUNK) || (l + 1 < NLAYER);
            if (haveC) {
                const int lc  = (ch + 2 < NCHUNK) ? l : l + 1;
                const int cc_ = (ch + 2 < NCHUNK) ? ch + 2 : ch + 2 - NCHUNK;
                const uint2* sC = sidx2 + (size_t)lc * (G_DIM / 2);
                const uint4* cC = hcf4  + (size_t)lc * (G_DIM / 2);
#pragma unroll
                for (int j = 0; j < 2; ++j) {
                    pkC[j] = sC[tid + (cc_ * 2 + j) * THREADS];
                    ccC[j] = cC[tid + (cc_ * 2 + j) * THREADS];
                }
            }
            float2 lwp[2];
            if (l == NLAYER - 1) {
#pragma unroll
                for (int j = 0; j < 2; ++j) lwp[j] = lw2[tid + (ch * 2 + j) * THREADS];
            }

            // pair A (= ch*2): gather-ahead pair B, then fma pair A
            GATHER(Gn, pkA[1]);
            if (l < NLAYER - 1) {
                const uint2 g0 = gate_fma(Gc.A0, Gc.B0, ccA[0].x, ccA[0].y);
                const uint2 g1 = gate_fma(Gc.A1, Gc.B1, ccA[0].z, ccA[0].w);
                o[ch * 2] = make_uint4(g0.x, g0.y, g1.x, g1.y);
            } else {
                gate_acc(Gc.A0, Gc.B0, ccA[0].x, ccA[0].y, lwp[0].x, a0, a1, a2, a3);
                gate_acc(Gc.A1, Gc.B1, ccA[0].z, ccA[0].w, lwp[0].y, a0, a1, a2, a3);
            }
            // pair B (= ch*2+1): gather-ahead next chunk's pair 0 (same layer only)
            if (ch + 1 < NCHUNK) GATHER(Gc, pkB[0]);
            if (l < NLAYER - 1) {
                const uint2 g0 = gate_fma(Gn.A0, Gn.B0, ccA[1].x, ccA[1].y);
                const uint2 g1 = gate_fma(Gn.A1, Gn.B1, ccA[1].z, ccA[1].w);
                o[ch * 2 + 1] = make_uint4(g0.x, g0.y, g1.x, g1.y);
            } else {
                gate_acc(Gn.A0, Gn.B0, ccA[1].x, ccA[1].y, lwp[1].x, a0, a1, a2, a3);
                gate_acc(Gn.A1, Gn.B1, ccA[1].z, ccA[1].w, lwp[1].y, a0, a1, a2, a3);
            }

            // rotate pipeline registers
#pragma unroll
            for (int j = 0; j < 2; ++j) {
                pkA[j] = pkB[j];
                ccA[j] = ccB[j];
                if (haveC) { pkB[j] = pkC[j]; ccB[j] = ccC[j]; }
            }
        }

        if (l < NLAYER - 1) {
            __syncthreads();   // all reads of this layer done
#pragma unroll
            for (int p = 0; p < NPAIR; ++p) buf4[tid + p * THREADS] = o[p];
            __syncthreads();   // layer fully materialized
        }
    }

    // cross-lane / cross-wave reduction (4 rows)
#pragma unroll
    for (int off = 32; off > 0; off >>= 1) {
        a0 += __shfl_down(a0, off);
        a1 += __shfl_down(a1, off);
        a2 += __shfl_down(a2, off);
        a3 += __shfl_down(a3, off);
    }
    const int lane = tid & 63, wid = tid >> 6;
    if (lane == 0) { red[0][wid] = a0; red[1][wid] = a1; red[2][wid] = a2; red[3][wid] = a3; }
    __syncthreads();
    if (tid < ROWS) {
        float s = 0.f;
#pragma unroll
        for (int k = 0; k < THREADS / 64; ++k) s += red[tid][k];
        out[row0 + tid] = s + lin_b[0];
    }
}

// ---- fallback (small ws): exact f32, inline softmax (correctness only) ----
__global__ __launch_bounds__(THREADS, 1) void fused_fallback_kernel(
    const float* __restrict__ x, Ptrs P,
    const float* __restrict__ lin_w, const float* __restrict__ lin_b,
    float* __restrict__ out)
{
    __shared__ float2 buf[G_DIM];
    __shared__ float red0[THREADS / 64];
    __shared__ float red1[THREADS / 64];
    const int tid  = threadIdx.x;
    const int row0 = blockIdx.x * 2;
    for (int i = tid; i < IN_DIM; i += THREADS)
        buf[i] = make_float2(x[(size_t)row0 * IN_DIM + i],
                             x[(size_t)(row0 + 1) * IN_DIM + i]);
    __syncthreads();
    float2 o[16];
    for (int l = 0; l < NLAYER; ++l) {
        const int2* __restrict__ idxl = (const int2*)P.idx[l];
#pragma unroll
        for (int i = 0; i < 16; ++i) {
            const int g = tid + i * THREADS;
            const int2 p = idxl[g];
            const float4 c = softmax_coef(P.w[l], g);
            const float2 Ap = buf[p.x];
            const float2 Bp = buf[p.y];
            o[i].x = fmaf(fmaf(c.w, Bp.x, c.y), Ap.x, fmaf(c.z, Bp.x, c.x));
            o[i].y = fmaf(fmaf(c.w, Bp.y, c.y), Ap.y, fmaf(c.z, Bp.y, c.x));
        }
        __syncthreads();
#pragma unroll
        for (int i = 0; i < 16; ++i) buf[tid + i * THREADS] = o[i];
        __syncthreads();
    }
    float a0 = 0.f, a1 = 0.f;
#pragma unroll
    for (int i = 0; i < 16; ++i) {
        const int g = tid + i * THREADS;
        const float lw = lin_w[g];
        const float2 bv = buf[g];
        a0 = fmaf(bv.x, lw, a0);
        a1 = fmaf(bv.y, lw, a1);
    }
#pragma unroll
    for (int off = 32; off > 0; off >>= 1) {
        a0 += __shfl_down(a0, off);
        a1 += __shfl_down(a1, off);
    }
    const int lane = tid & 63, wid = tid >> 6;
    if (lane == 0) { red0[wid] = a0; red1[wid] = a1; }
    __syncthreads();
    if (tid == 0) {
        float s0 = 0.f, s1 = 0.f;
#pragma unroll
        for (int k = 0; k < THREADS / 64; ++k) { s0 += red0[k]; s1 += red1[k]; }
        const float lb = lin_b[0];
        out[row0]     = s0 + lb;
        out[row0 + 1] = s1 + lb;
    }
}

extern "C" void kernel_launch(void* const* d_in, const int* in_sizes, int n_in,
                              void* d_out, int out_size, void* d_ws, size_t ws_size,
                              hipStream_t stream) {
    // layout: [x, idx0, w0, idx1, w1, ..., idx5, w5, lin_w, lin_b]
    const float* x = (const float*)d_in[0];
    Ptrs P;
    for (int l = 0; l < NLAYER; ++l) {
        P.idx[l] = (const int*)d_in[1 + 2 * l];
        P.w[l]   = (const float*)d_in[2 + 2 * l];
    }
    const float* lin_w = (const float*)d_in[13];
    const float* lin_b = (const float*)d_in[14];
    float* out = (float*)d_out;

    const size_t hcf_bytes  = (size_t)NLAYER * G_DIM * sizeof(uint2);
    const size_t sidx_bytes = (size_t)NLAYER * G_DIM * sizeof(unsigned);
    if (ws_size >= hcf_bytes + sidx_bytes) {
        uint2*    hcf  = (uint2*)d_ws;
        unsigned* sidx = (unsigned*)((char*)d_ws + hcf_bytes);
        dim3 cgrid(G_DIM / 256, NLAYER);
        pack_kernel<<<cgrid, 256, 0, stream>>>(P, hcf, sidx);
        fused_ws_kernel<<<N_BATCH / ROWS, THREADS, 0, stream>>>(
            x, hcf, sidx, lin_w, lin_b, out);
    } else {
        fused_fallback_kernel<<<N_BATCH / 2, THREADS, 0, stream>>>(
            x, P, lin_w, lin_b, out);
    }
}